// Round 1
// baseline (9.730 us; speedup 1.0000x reference)
//
#include <hip/hip_runtime.h>

// LinearClassification: loss = -2 * mean(out * one_hot(label))
//                            = -2 * sum_i out[i, label[i]] / (B * V)
// B = 4096, V = 50257. Only 4096 gathered elements matter -> single tiny
// gather+reduce kernel. Accumulate in double for bit-tight accuracy
// (threshold is ~8e-9 absolute on a ~4e-7 result).

__global__ __launch_bounds__(1024)
void LinearClassification_71167608095256_kernel(const float* __restrict__ outm,
                                                const int* __restrict__ lab32,
                                                float* __restrict__ res,
                                                int B, long long V) {
    const int tid      = threadIdx.x;
    const int nthreads = blockDim.x;
    const int lane     = tid & 63;
    const int wave     = tid >> 6;
    const int nwaves   = (nthreads + 63) >> 6;

    __shared__ int    s_nz[16];
    __shared__ int    s_is64;
    __shared__ double s_part[16];

    // --- Detect label storage: int32 (one word per label) vs little-endian
    // int64 ([lo, 0] pairs). If int64, every odd 32-bit word among the first
    // B words is the zero high-half of a label (labels in [0, 50257)). With
    // random int32 labels the odd words are random values, essentially never
    // all zero. Reads stay within the first B words -> in-bounds either way.
    int nonzero = 0;
    for (int j = 2 * tid + 1; j < B; j += 2 * nthreads)
        nonzero |= (lab32[j] != 0);
    unsigned long long ball = __ballot(nonzero);
    if (lane == 0) s_nz[wave] = (ball != 0ull) ? 1 : 0;
    __syncthreads();
    if (tid == 0) {
        int nz = 0;
        for (int w = 0; w < nwaves; ++w) nz |= s_nz[w];
        s_is64 = (nz == 0);   // all odd words zero -> int64 layout
    }
    __syncthreads();
    const bool is64 = (s_is64 != 0);

    // --- Gather + per-thread accumulate in double (4 gathers/thread).
    double acc = 0.0;
    for (int i = tid; i < B; i += nthreads) {
        const long long idx = (long long)(is64 ? lab32[2 * i] : lab32[i]);
        acc += (double)outm[(long long)i * V + idx];
    }

    // --- Deterministic reduction: wave shuffle tree, then LDS across waves.
    #pragma unroll
    for (int off = 32; off > 0; off >>= 1)
        acc += __shfl_down(acc, off, 64);
    if (lane == 0) s_part[wave] = acc;
    __syncthreads();
    if (tid == 0) {
        double t = 0.0;
        for (int w = 0; w < nwaves; ++w) t += s_part[w];
        res[0] = (float)(-2.0 * t / ((double)B * (double)V));
    }
}

extern "C" void kernel_launch(void* const* d_in, const int* in_sizes, int n_in,
                              void* d_out, int out_size, void* d_ws, size_t ws_size,
                              hipStream_t stream) {
    const float* outm = (const float*)d_in[0];
    const int*   lab  = (const int*)d_in[1];
    float*       res  = (float*)d_out;

    const int B = in_sizes[1];                       // 4096
    const long long V = (long long)in_sizes[0] / B;  // 50257

    LinearClassification_71167608095256_kernel<<<1, 1024, 0, stream>>>(
        outm, lab, res, B, V);
}

// Round 2
// 9.665 us; speedup vs baseline: 1.0066x; 1.0066x over previous
//
#include <hip/hip_runtime.h>

// LinearClassification: loss = -2 * sum_i out[i, label[i]] / (B * V)
// B = 4096, V = 50257. Only 4096 scattered fp32 gathers matter. Latency-bound:
// structure so ALL memory ops (layout-detect loads, label loads, gathers) are
// in flight concurrently, with no dependent chains. fp64 accumulation keeps
// summation error ~1e-15 vs the 8e-9 absolute threshold.

__global__ __launch_bounds__(1024)
void LinearClassification_71167608095256_kernel(const float* __restrict__ outm,
                                                const int* __restrict__ lab32,
                                                float* __restrict__ res,
                                                int B, long long V) {
    const int tid      = threadIdx.x;
    const int nthreads = blockDim.x;
    const int lane     = tid & 63;
    const int wave     = tid >> 6;
    const int nwaves   = (nthreads + 63) >> 6;

    __shared__ int    s_nz[16];
    __shared__ int    s_is64;
    __shared__ double s_part[16];

    constexpr int MAXI = 8;                    // supports B <= 8 * nthreads

    // ---- Issue ALL loads up front, independent of each other ----

    // (a) layout-detection loads: odd 32-bit words among the first B words.
    //     int64-LE layout => all are zero high-halves; int32 => random labels.
    int nonzero = 0;
    #pragma unroll
    for (int k = 0; k < MAXI / 2; ++k) {
        int j = 2 * (tid + k * nthreads) + 1;
        if (j < B) nonzero |= (lab32[j] != 0);
    }

    // (b) speculative int32-layout label loads (word i is in-bounds for both
    //     layouts since i < B).
    int labv[MAXI];
    #pragma unroll
    for (int k = 0; k < MAXI; ++k) {
        int i = tid + k * nthreads;
        if (i < B) labv[k] = lab32[i];
    }

    // (c) speculative gathers. Under int64 layout labv[k] is either a valid
    //     label (< V) or 0 -> always in-bounds; values discarded in that case.
    float gv[MAXI];
    #pragma unroll
    for (int k = 0; k < MAXI; ++k) {
        int i = tid + k * nthreads;
        if (i < B) gv[k] = outm[(long long)i * V + labv[k]];
    }

    // ---- Resolve detection (overlapped with the loads above) ----
    unsigned long long ball = __ballot(nonzero);
    if (lane == 0) s_nz[wave] = (ball != 0ull) ? 1 : 0;
    __syncthreads();
    if (tid == 0) {
        int nz = 0;
        for (int w = 0; w < nwaves; ++w) nz |= s_nz[w];
        s_is64 = (nz == 0);   // all odd words zero -> int64 layout
    }
    __syncthreads();

    // ---- Accumulate (fast path: int32 layout, speculation valid) ----
    double acc = 0.0;
    if (!s_is64) {
        #pragma unroll
        for (int k = 0; k < MAXI; ++k) {
            int i = tid + k * nthreads;
            if (i < B) acc += (double)gv[k];
        }
    } else {
        // Slow path (int64 layout): reload correct indices, re-gather.
        int lv[MAXI];
        #pragma unroll
        for (int k = 0; k < MAXI; ++k) {
            int i = tid + k * nthreads;
            if (i < B) lv[k] = lab32[2 * i];
        }
        #pragma unroll
        for (int k = 0; k < MAXI; ++k) {
            int i = tid + k * nthreads;
            if (i < B) acc += (double)outm[(long long)i * V + lv[k]];
        }
    }

    // ---- Deterministic reduction: wave shuffle tree, then LDS ----
    #pragma unroll
    for (int off = 32; off > 0; off >>= 1)
        acc += __shfl_down(acc, off, 64);
    if (lane == 0) s_part[wave] = acc;
    __syncthreads();
    if (tid == 0) {
        double t = 0.0;
        for (int w = 0; w < nwaves; ++w) t += s_part[w];
        res[0] = (float)(-2.0 * t / ((double)B * (double)V));
    }
}

extern "C" void kernel_launch(void* const* d_in, const int* in_sizes, int n_in,
                              void* d_out, int out_size, void* d_ws, size_t ws_size,
                              hipStream_t stream) {
    const float* outm = (const float*)d_in[0];
    const int*   lab  = (const int*)d_in[1];
    float*       res  = (float*)d_out;

    const int B = in_sizes[1];                       // 4096
    const long long V = (long long)in_sizes[0] / B;  // 50257

    LinearClassification_71167608095256_kernel<<<1, 1024, 0, stream>>>(
        outm, lab, res, B, V);
}